// Round 1
// baseline (260.123 us; speedup 1.0000x reference)
//
#include <hip/hip_runtime.h>

#define BATCH 16
#define TFRAMES 2000
#define BINS 513
#define NFFT 1024
#define STEP 256
#define OUT_LEN 512768            // (TFRAMES-1)*STEP + NFFT
#define M_TOTAL (BATCH*TFRAMES)   // 32000
// K layout (pairs, 2 halves each): pair 0 = DC/Nyquist trick:
//   A[m][0]=(re[m,0]/1024, re[m,512]/1024), B[n][0]=(1, (-1)^n)
//   -> dot = (re0 + (-1)^n re512)/1024, exactly the bin-0 + bin-512 term.
// pairs p=1..511: A=(re[m,p]/512, -im[m,p]/512), B=(cos[n,p], sin[n,p]).
// KP = 2*512 = 1024 halves: 16 iters of BK=64, zero waste.
#define KP 1024
#define PAIRS 512
#define JPACK 128                 // uint4 groups (4 pairs) per packed A row

typedef _Float16 f16x8 __attribute__((ext_vector_type(8)));
typedef float    f32x4 __attribute__((ext_vector_type(4)));

// ---------------- pack kernels ----------------
__global__ __launch_bounds__(256) void pack_A(const float* __restrict__ sre,
                                              const float* __restrict__ sim,
                                              uint4* __restrict__ Au)
{
    const int idx = blockIdx.x * 256 + threadIdx.x;   // m*JPACK + j, exact grid
    const int m = idx >> 7;
    const int j = idx & 127;
    const int k0 = j * 4;                             // pair index of group start
    const size_t base = (size_t)m * BINS + k0;        // bin==pair for j>=1 lanes
    union { _Float16 h[8]; uint4 u; } pk;
    if (j == 0) {
        // pairs 0..3: pair0 = DC/Nyquist, pairs 1..3 = bins 1..3
        const float re0   = sre[(size_t)m * BINS];
        const float re512 = sre[(size_t)m * BINS + 512];
        pk.h[0] = (_Float16)(re0   * (1.0f/1024.0f));
        pk.h[1] = (_Float16)(re512 * (1.0f/1024.0f));
        #pragma unroll
        for (int i = 1; i < 4; i++) {
            pk.h[2*i]   = (_Float16)( sre[base + i] * (1.0f/512.0f));
            pk.h[2*i+1] = (_Float16)(-sim[base + i] * (1.0f/512.0f));
        }
    } else {
        // bins 4j..4j+3, all within 4..511 -> no guards
        #pragma unroll
        for (int i = 0; i < 4; i++) {
            pk.h[2*i]   = (_Float16)( sre[base + i] * (1.0f/512.0f));
            pk.h[2*i+1] = (_Float16)(-sim[base + i] * (1.0f/512.0f));
        }
    }
    Au[idx] = pk.u;
}

__global__ __launch_bounds__(256) void pack_B(const float* __restrict__ dcos,
                                              const float* __restrict__ dsin,
                                              unsigned* __restrict__ Bu)
{
    const int idx = blockIdx.x * 256 + threadIdx.x;   // n*PAIRS + p, exact grid
    const int n = idx >> 9;
    const int p = idx & 511;
    float b0, b1;
    if (p == 0) {
        b0 = 1.0f;
        b1 = (n & 1) ? -1.0f : 1.0f;                  // cos[n][512] = (-1)^n
    } else {
        const size_t base = (size_t)n * NFFT + p;
        b0 = dcos[base];
        b1 = dsin[base];
    }
    union { _Float16 h[2]; unsigned u; } pk;
    pk.h[0] = (_Float16)b0;
    pk.h[1] = (_Float16)b1;
    Bu[idx] = pk.u;
}

__device__ __forceinline__ void async_copy16(const void* g, void* l) {
    __builtin_amdgcn_global_load_lds(
        (const __attribute__((address_space(1))) unsigned*)g,
        (__attribute__((address_space(3))) unsigned*)l, 16, 0, 0);
}

// ---------------- legacy 128x128 MFMA GEMM (kept as atomic-path fallback) ----
#define BM 128
#define BN 128
#define BK 64

template<bool USE_FRAMES>
__global__ __launch_bounds__(256, 3) void gemm_f16(const _Float16* __restrict__ A,
                                                   const _Float16* __restrict__ B,
                                                   const float* __restrict__ window,
                                                   _Float16* __restrict__ frames,
                                                   float* __restrict__ out)
{
    __shared__ _Float16 As[BM * BK];   // 16 KB
    __shared__ _Float16 Bs[BN * BK];   // 16 KB

    const int raw = blockIdx.x;                    // 0..1999
    const int idx = (raw & 7) * 250 + (raw >> 3);  // bijection
    const int mt = idx >> 3;                       // 0..249
    const int nt = idx & 7;                        // 0..7
    const int m0 = mt * BM;
    const int n0 = nt * BN;

    const int tid  = threadIdx.x;
    const int w    = tid >> 6;         // wave 0..3
    const int lane = tid & 63;
    const int wm   = w & 1;            // wave's 64x64 quadrant
    const int wn   = w >> 1;
    const int row16 = lane & 15;
    const int quad  = lane >> 4;

    const int srow   = lane >> 3;                    // 0..7
    const int schunk = (lane & 7) ^ srow;            // swizzled chunk for this lane
    const _Float16* gA = A + (size_t)(m0 + w*32 + srow) * KP + schunk * 8;
    const _Float16* gB = B + (size_t)(n0 + w*32 + srow) * KP + schunk * 8;

    f32x4 acc[4][4] = {};

    for (int k0 = 0; k0 < KP; k0 += BK) {
        #pragma unroll
        for (int t = 0; t < 4; t++) {
            async_copy16(gA + (size_t)t*8*KP + k0, As + (w*4 + t) * 512);
            async_copy16(gB + (size_t)t*8*KP + k0, Bs + (w*4 + t) * 512);
        }
        __syncthreads();               // drain staging

        #pragma unroll
        for (int c = 0; c < 2; c++) {
            f16x8 af[4], bf[4];
            #pragma unroll
            for (int i = 0; i < 4; i++) {
                const int rowA = wm*64 + i*16 + row16;
                const int chA  = (c*4 + quad) ^ (row16 & 7);
                af[i] = *(const f16x8*)&As[rowA * BK + chA * 8];
            }
            #pragma unroll
            for (int j = 0; j < 4; j++) {
                const int rowB = wn*64 + j*16 + row16;
                const int chB  = (c*4 + quad) ^ (row16 & 7);
                bf[j] = *(const f16x8*)&Bs[rowB * BK + chB * 8];
            }
            #pragma unroll
            for (int i = 0; i < 4; i++)
                #pragma unroll
                for (int j = 0; j < 4; j++)
                    acc[i][j] = __builtin_amdgcn_mfma_f32_16x16x32_f16(af[i], bf[j], acc[i][j], 0, 0, 0);
        }

        __syncthreads();
    }

    #pragma unroll
    for (int j = 0; j < 4; j++) {
        const int n = n0 + wn*64 + j*16 + row16;
        const float win = window[n];
        #pragma unroll
        for (int i = 0; i < 4; i++) {
            const int mrow = m0 + wm*64 + i*16 + quad*4;
            const f32x4 c = acc[i][j];
            if (USE_FRAMES) {
                #pragma unroll
                for (int r = 0; r < 4; r++)
                    frames[(size_t)(mrow + r) * NFFT + n] = (_Float16)(c[r] * win);
            } else {
                #pragma unroll
                for (int r = 0; r < 4; r++) {
                    const int m = mrow + r;
                    const int b = m / TFRAMES;
                    const int t = m - b * TFRAMES;
                    atomicAdd(&out[(size_t)b * OUT_LEN + (size_t)t * STEP + n], c[r] * win);
                }
            }
        }
    }
}

// ---------------- 256x256 8-phase MFMA GEMM (T3+T4+T5 per m194-m201) --------
// 8 waves (2M x 4N), 512 threads, BK=64, double-buffered 128 KiB LDS,
// counted vmcnt(8) at tile boundaries (never 0 in steady state),
// chunk-XOR swizzle (slot = chunk ^ (row&7)) applied on the GLOBAL side,
// verified conflict-free in earlier rounds.
#define BM2 256
#define BN2 256
#define BK2 64
#define NTILES 16                 // KP / BK2

#define PRE_MFMA()  do { __builtin_amdgcn_sched_barrier(0); \
                         __builtin_amdgcn_s_barrier(); \
                         asm volatile("s_waitcnt lgkmcnt(0)" ::: "memory"); \
                         __builtin_amdgcn_sched_barrier(0); \
                         __builtin_amdgcn_s_setprio(1); } while (0)
#define POST_MFMA() do { __builtin_amdgcn_s_setprio(0); \
                         __builtin_amdgcn_sched_barrier(0); \
                         __builtin_amdgcn_s_barrier(); } while (0)

#define MFMA_Q(I0, J0) \
    do { _Pragma("unroll") for (int ks = 0; ks < 2; ++ks) { \
         _Pragma("unroll") for (int ii = 0; ii < 4; ++ii) { \
           _Pragma("unroll") for (int jj = 0; jj < 2; ++jj) { \
             acc[(I0)+ii][(J0)+jj] = __builtin_amdgcn_mfma_f32_16x16x32_f16( \
                 af[(I0)+ii][ks], bf[(J0)+jj][ks], acc[(I0)+ii][(J0)+jj], 0, 0, 0); \
         } } } } while (0)

__global__ __launch_bounds__(512, 2) void gemm_f16_8p(const _Float16* __restrict__ A,
                                                      const _Float16* __restrict__ B,
                                                      const float* __restrict__ window,
                                                      _Float16* __restrict__ frames)
{
    __shared__ _Float16 As[2][BM2 * BK2];   // 2 x 32 KB
    __shared__ _Float16 Bs[2][BN2 * BK2];   // 2 x 32 KB

    // Bijective XCD swizzle over 500 wgs (500 % 8 != 0 -> m204 variant).
    // q = 62, r = 4: xcd<4 get 63 wgs, else 62. Consecutive wg share mt.
    const int raw = blockIdx.x;
    const int xcd = raw & 7;
    const int loc = raw >> 3;
    const int wg  = (xcd < 4 ? xcd * 63 : 252 + (xcd - 4) * 62) + loc;
    const int mt = wg >> 2;                 // 0..124
    const int nt = wg & 3;                  // 0..3
    const int m0 = mt * BM2;
    const int n0 = nt * BN2;

    const int tid  = threadIdx.x;
    const int w    = tid >> 6;              // wave 0..7
    const int lane = tid & 63;
    const int wm   = w >> 2;                // 0..1 -> rows wm*128..+127
    const int wn   = w & 3;                 // 0..3 -> cols wn*64..+63
    const int row16 = lane & 15;
    const int quad  = lane >> 4;
    const int sw    = row16 & 7;            // read-side swizzle key

    // staging: thread covers row (slot*64 + r64), 16B chunk schunk (pre-swizzled)
    const int r64    = tid >> 3;                       // 0..63
    const int schunk = (tid & 7) ^ (r64 & 7);
    const _Float16* gA = A + (size_t)(m0 + r64) * KP + schunk * 8;
    const _Float16* gB = B + (size_t)(n0 + r64) * KP + schunk * 8;

    // ---- prologue: stage tiles 0 (buf0) and 1 (buf1), wait tile 0 only ----
    #pragma unroll
    for (int s = 0; s < 4; ++s) {
        async_copy16(gA + (size_t)s*64*KP,       &As[0][s*4096 + w*512]);
        async_copy16(gB + (size_t)s*64*KP,       &Bs[0][s*4096 + w*512]);
    }
    #pragma unroll
    for (int s = 0; s < 4; ++s) {
        async_copy16(gA + (size_t)s*64*KP + BK2, &As[1][s*4096 + w*512]);
        async_copy16(gB + (size_t)s*64*KP + BK2, &Bs[1][s*4096 + w*512]);
    }
    asm volatile("s_waitcnt vmcnt(8)" ::: "memory");   // tile 0 landed; tile 1 in flight
    __builtin_amdgcn_sched_barrier(0);
    __builtin_amdgcn_s_barrier();

    f32x4 acc[8][4] = {};

    for (int kt = 0; kt < NTILES; ++kt) {
        const int buf = kt & 1;
        const _Float16* as = As[buf];
        const _Float16* bs = Bs[buf];
        f16x8 af[8][2];
        f16x8 bf[4][2];
        const int arow0 = wm*128 + row16;
        const int brow0 = wn*64  + row16;

        // ---- P0: read af[0..3], bf[0..1]; MFMA (Mlo, Nlo) ----
        #pragma unroll
        for (int ii = 0; ii < 4; ++ii)
            #pragma unroll
            for (int ks = 0; ks < 2; ++ks)
                af[ii][ks] = *(const f16x8*)&as[(arow0 + ii*16)*BK2 + ((ks*4 + quad) ^ sw)*8];
        #pragma unroll
        for (int jj = 0; jj < 2; ++jj)
            #pragma unroll
            for (int ks = 0; ks < 2; ++ks)
                bf[jj][ks] = *(const f16x8*)&bs[(brow0 + jj*16)*BK2 + ((ks*4 + quad) ^ sw)*8];
        PRE_MFMA();
        MFMA_Q(0, 0);
        POST_MFMA();

        // ---- P1: read af[4..7], bf[2..3]; MFMA (Mhi, Nhi) ----
        #pragma unroll
        for (int ii = 0; ii < 4; ++ii)
            #pragma unroll
            for (int ks = 0; ks < 2; ++ks)
                af[4+ii][ks] = *(const f16x8*)&as[(arow0 + 64 + ii*16)*BK2 + ((ks*4 + quad) ^ sw)*8];
        #pragma unroll
        for (int jj = 0; jj < 2; ++jj)
            #pragma unroll
            for (int ks = 0; ks < 2; ++ks)
                bf[2+jj][ks] = *(const f16x8*)&bs[(brow0 + (2+jj)*16)*BK2 + ((ks*4 + quad) ^ sw)*8];
        PRE_MFMA();
        MFMA_Q(4, 2);
        POST_MFMA();
        // After this barrier every wave has retired ALL reads of buf -> safe to overwrite.

        // ---- P2: stage half of tile kt+2 into this buf; MFMA (Mhi, Nlo) ----
        if (kt < NTILES-2) {
            const int nk = (kt + 2) * BK2;
            async_copy16(gA + nk,                    &As[buf][0*4096 + w*512]);
            async_copy16(gA + (size_t)64*KP  + nk,   &As[buf][1*4096 + w*512]);
            async_copy16(gB + nk,                    &Bs[buf][0*4096 + w*512]);
            async_copy16(gB + (size_t)64*KP  + nk,   &Bs[buf][1*4096 + w*512]);
        }
        PRE_MFMA();
        MFMA_Q(4, 0);
        POST_MFMA();

        // ---- P3: stage other half; MFMA (Mlo, Nhi); counted vmcnt ----
        if (kt < NTILES-2) {
            const int nk = (kt + 2) * BK2;
            async_copy16(gA + (size_t)128*KP + nk,   &As[buf][2*4096 + w*512]);
            async_copy16(gA + (size_t)192*KP + nk,   &As[buf][3*4096 + w*512]);
            async_copy16(gB + (size_t)128*KP + nk,   &Bs[buf][2*4096 + w*512]);
            async_copy16(gB + (size_t)192*KP + nk,   &Bs[buf][3*4096 + w*512]);
        }
        PRE_MFMA();
        MFMA_Q(0, 2);
        __builtin_amdgcn_s_setprio(0);
        __builtin_amdgcn_sched_barrier(0);
        if (kt < NTILES-2) {
            asm volatile("s_waitcnt vmcnt(8)" ::: "memory");   // tile kt+1 landed; kt+2 in flight
        } else if (kt == NTILES-2) {
            asm volatile("s_waitcnt vmcnt(0)" ::: "memory");   // last tile's loads
        }
        __builtin_amdgcn_sched_barrier(0);
        __builtin_amdgcn_s_barrier();
    }

    // ---- epilogue: window + f16 frames store (C/D: col=lane&15, row=quad*4+r)
    #pragma unroll
    for (int j = 0; j < 4; ++j) {
        const int n = n0 + wn*64 + j*16 + row16;
        const float win = window[n];
        #pragma unroll
        for (int i = 0; i < 8; ++i) {
            const int mrow = m0 + wm*128 + i*16 + quad*4;
            const f32x4 c = acc[i][j];
            #pragma unroll
            for (int r = 0; r < 4; ++r)
                frames[(size_t)(mrow + r) * NFFT + n] = (_Float16)(c[r] * win);
        }
    }
}

// ---------------- deterministic overlap-add gather (r4, verified) ----------------
#define OLA_G 64096   // OUT_LEN/8
__global__ __launch_bounds__(256) void ola_gather(const _Float16* __restrict__ frames,
                                                  float* __restrict__ out)
{
    const int idx = blockIdx.x * 256 + threadIdx.x;   // b*OLA_G + r, exact grid
    const int b = idx / OLA_G;
    const int r = idx - b * OLA_G;
    const int s0 = r << 3;
    int tlo = (s0 - 768) >> 8;  if (tlo < 0) tlo = 0;
    int thi = s0 >> 8;          if (thi > TFRAMES-1) thi = TFRAMES-1;
    float sum[8] = {};
    for (int t = tlo; t <= thi; ++t) {
        const f16x8 f = *(const f16x8*)&frames[((size_t)b * TFRAMES + t) * NFFT + (s0 - (t << 8))];
        #pragma unroll
        for (int i = 0; i < 8; i++) sum[i] += (float)f[i];
    }
    f32x4* o = (f32x4*)(out + (size_t)b * OUT_LEN + s0);
    o[0] = (f32x4){sum[0], sum[1], sum[2], sum[3]};
    o[1] = (f32x4){sum[4], sum[5], sum[6], sum[7]};
}

// ---------------- round-1 fp32 fallback (known-correct) ----------------
#define MT 64
#define NT 64
#define KT 16
#define PAD 4
__global__ __launch_bounds__(256) void istft_gemm_ola_f32(
    const float* __restrict__ sre, const float* __restrict__ sim,
    const float* __restrict__ dcos, const float* __restrict__ dsin,
    const float* __restrict__ window, float* __restrict__ out)
{
    __shared__ float As_re[KT][MT + PAD];
    __shared__ float As_im[KT][MT + PAD];
    __shared__ float Bs_c[KT][NT + PAD];
    __shared__ float Bs_s[KT][NT + PAD];
    const int ntile = blockIdx.x & 15;
    const int mtile = blockIdx.x >> 4;
    const int m0 = mtile * MT, n0 = ntile * NT;
    const int tid = threadIdx.x;
    const int tx = tid & 15, ty = tid >> 4;
    const int lcol = tid & 15, lrow = tid >> 4;
    float acc[4][4] = {};
    for (int k0 = 0; k0 < BINS; k0 += KT) {
        const int k = k0 + lcol;
        const bool kvalid = (k < BINS);
        const float w = kvalid ? ((k == 0 || k == 512) ? (1.0f/1024.0f) : (2.0f/1024.0f)) : 0.0f;
        #pragma unroll
        for (int i = 0; i < 4; i++) {
            const int m = m0 + lrow + i*16;
            const size_t base = (size_t)m * BINS + k;
            As_re[lcol][lrow + i*16] = kvalid ?  w * sre[base] : 0.0f;
            As_im[lcol][lrow + i*16] = kvalid ? -w * sim[base] : 0.0f;
        }
        #pragma unroll
        for (int i = 0; i < 4; i++) {
            const int n = n0 + lrow + i*16;
            const size_t base = (size_t)n * NFFT + k;
            Bs_c[lcol][lrow + i*16] = kvalid ? dcos[base] : 0.0f;
            Bs_s[lcol][lrow + i*16] = kvalid ? dsin[base] : 0.0f;
        }
        __syncthreads();
        #pragma unroll
        for (int kk = 0; kk < KT; kk++) {
            const float4 ar = *(const float4*)&As_re[kk][ty*4];
            const float4 ai = *(const float4*)&As_im[kk][ty*4];
            const float4 bc = *(const float4*)&Bs_c[kk][tx*4];
            const float4 bs = *(const float4*)&Bs_s[kk][tx*4];
            const float a_r[4] = {ar.x, ar.y, ar.z, ar.w};
            const float a_i[4] = {ai.x, ai.y, ai.z, ai.w};
            const float b_c[4] = {bc.x, bc.y, bc.z, bc.w};
            const float b_s[4] = {bs.x, bs.y, bs.z, bs.w};
            #pragma unroll
            for (int i = 0; i < 4; i++)
                #pragma unroll
                for (int j = 0; j < 4; j++)
                    acc[i][j] += a_r[i]*b_c[j] + a_i[i]*b_s[j];
        }
        __syncthreads();
    }
    #pragma unroll
    for (int i = 0; i < 4; i++) {
        const int m = m0 + ty*4 + i;
        const int b = m / TFRAMES;
        const int t = m - b * TFRAMES;
        const size_t obase = (size_t)b * OUT_LEN + (size_t)t * STEP;
        #pragma unroll
        for (int j = 0; j < 4; j++) {
            const int n = n0 + tx*4 + j;
            atomicAdd(&out[obase + n], acc[i][j] * window[n]);
        }
    }
}

// ---------------- launch ----------------
extern "C" void kernel_launch(void* const* d_in, const int* in_sizes, int n_in,
                              void* d_out, int out_size, void* d_ws, size_t ws_size,
                              hipStream_t stream) {
    const float* sre    = (const float*)d_in[0];
    const float* sim    = (const float*)d_in[1];
    const float* dcos   = (const float*)d_in[2];
    const float* dsin   = (const float*)d_in[3];
    const float* window = (const float*)d_in[4];
    float* out = (float*)d_out;

    const size_t WS_A      = (size_t)M_TOTAL * KP * sizeof(_Float16);    // 65,536,000
    const size_t WS_B      = (size_t)NFFT    * KP * sizeof(_Float16);    //  2,097,152
    const size_t WS_FRAMES = (size_t)M_TOTAL * NFFT * sizeof(_Float16);  // 65,536,000

    if (ws_size >= WS_A + WS_B) {
        _Float16* Apk    = (_Float16*)d_ws;
        _Float16* Bpk    = (_Float16*)((char*)d_ws + WS_A);
        _Float16* frames = (_Float16*)((char*)d_ws + WS_A + WS_B);
        const bool have_frames = (ws_size >= WS_A + WS_B + WS_FRAMES);

        pack_A<<<(M_TOTAL * JPACK) / 256, 256, 0, stream>>>(sre, sim, (uint4*)Apk);
        pack_B<<<(NFFT * PAIRS) / 256, 256, 0, stream>>>(dcos, dsin, (unsigned*)Bpk);

        if (have_frames) {
            const int grid8 = (M_TOTAL / BM2) * (NFFT / BN2);  // 125 * 4 = 500
            gemm_f16_8p<<<grid8, 512, 0, stream>>>(Apk, Bpk, window, frames);
            ola_gather<<<(BATCH * OUT_LEN) / 2048, 256, 0, stream>>>(frames, out);
        } else {
            hipMemsetAsync(out, 0, (size_t)out_size * sizeof(float), stream);
            const int grid = (M_TOTAL / BM) * (NFFT / BN);     // 250 * 8 = 2000
            gemm_f16<false><<<grid, 256, 0, stream>>>(Apk, Bpk, window, nullptr, out);
        }
    } else {
        hipMemsetAsync(out, 0, (size_t)out_size * sizeof(float), stream);
        const int grid = (M_TOTAL / MT) * (NFFT / NT);
        istft_gemm_ola_f32<<<grid, 256, 0, stream>>>(sre, sim, dcos, dsin, window, out);
    }
}

// Round 2
// 257.515 us; speedup vs baseline: 1.0101x; 1.0101x over previous
//
#include <hip/hip_runtime.h>

#define BATCH 16
#define TFRAMES 2000
#define BINS 513
#define NFFT 1024
#define STEP 256
#define OUT_LEN 512768            // (TFRAMES-1)*STEP + NFFT
#define M_TOTAL (BATCH*TFRAMES)   // 32000

// ---- legacy packed layout (fallback atomic path) ----
#define KP 1024
#define PAIRS 512
#define JPACK 128

// ---- symmetry-split layout (fast path) ----
// C[n] = sum_p Ar[p]*cos(2pi p n/1024), Ar[0]=re0/1024 (B_cos[n][0]=1), Ar[p]=re[p]/512
// S[n] = sum_p Ai[p]*sin(2pi p n/1024), Ai[p]=-im[p]/512, slot 0 dead (B_sin[n][0]=0)
// x[n]      = C[n]+S[n]+t,  x[1024-n] = C[n]-S[n]+t,  t=(-1)^n*re512/1024, n=0..511
// x[512]    = sum_k (-1)^k Ar[k] + re512/1024   (fused into pack_A2 wave-reduce)
#define KP2 512

typedef _Float16 f16x8 __attribute__((ext_vector_type(8)));
typedef float    f32x4 __attribute__((ext_vector_type(4)));

__device__ __forceinline__ void async_copy16(const void* g, void* l) {
    __builtin_amdgcn_global_load_lds(
        (const __attribute__((address_space(1))) unsigned*)g,
        (__attribute__((address_space(3))) unsigned*)l, 16, 0, 0);
}

// ---------------- fast-path pack kernels ----------------
// one wave (64 threads) per row m; thread j handles k = 8j..8j+7
__global__ __launch_bounds__(256) void pack_A2(const float* __restrict__ sre,
                                               const float* __restrict__ sim,
                                               const float* __restrict__ window,
                                               uint4* __restrict__ Ar,
                                               uint4* __restrict__ Ai,
                                               float* __restrict__ re512f,
                                               _Float16* __restrict__ frames)
{
    const int idx = blockIdx.x * 256 + threadIdx.x;   // m*64 + j, exact grid
    const int m = idx >> 6;
    const int j = idx & 63;
    const int k0 = j * 8;
    const size_t base = (size_t)m * BINS + k0;
    float ar[8], ai[8];
    #pragma unroll
    for (int i = 0; i < 8; i++) {
        ar[i] =  sre[base + i] * (1.0f/512.0f);
        ai[i] = -sim[base + i] * (1.0f/512.0f);
    }
    float r5 = 0.0f;
    if (j == 0) {
        ar[0] = sre[(size_t)m * BINS] * (1.0f/1024.0f);   // DC slot, B_cos[n][0]=1
        ai[0] = 0.0f;                                      // dead slot, B_sin[n][0]=0
        r5 = sre[(size_t)m * BINS + 512] * (1.0f/1024.0f);
        re512f[m] = r5;
    }
    union { _Float16 h[8]; uint4 u; } pr, pi;
    #pragma unroll
    for (int i = 0; i < 8; i++) { pr.h[i] = (_Float16)ar[i]; pi.h[i] = (_Float16)ai[i]; }
    Ar[idx] = pr.u;
    Ai[idx] = pi.u;

    // fused n=512 column: x[512] = sum_k (-1)^k Ar[k] + re512/1024 (f32 accumulate)
    float s = ar[0]-ar[1]+ar[2]-ar[3]+ar[4]-ar[5]+ar[6]-ar[7];
    #pragma unroll
    for (int off = 32; off > 0; off >>= 1) s += __shfl_xor(s, off);
    if (j == 0)
        frames[(size_t)m * NFFT + 512] = (_Float16)((s + r5) * window[512]);
}

__global__ __launch_bounds__(256) void pack_B2(const float* __restrict__ dcos,
                                               const float* __restrict__ dsin,
                                               uint4* __restrict__ Bc,
                                               uint4* __restrict__ Bs)
{
    const int idx = blockIdx.x * 256 + threadIdx.x;   // n*64 + j, exact grid (128 blocks)
    const int n = idx >> 6;
    const int j = idx & 63;
    const int k0 = j * 8;
    const size_t base = (size_t)n * NFFT + k0;
    union { _Float16 h[8]; uint4 u; } pc, ps;
    #pragma unroll
    for (int i = 0; i < 8; i++) {
        pc.h[i] = (_Float16)dcos[base + i];
        ps.h[i] = (_Float16)dsin[base + i];
    }
    if (j == 0) { pc.h[0] = (_Float16)1.0f; ps.h[0] = (_Float16)0.0f; }
    Bc[idx] = pc.u;
    Bs[idx] = ps.u;
}

// ---------------- dual-accumulator symmetry GEMM (proven m97-structure) -----
// Block: 128(M) x 64(N of half-domain), 2x2 waves, BK=32 per matrix.
// LDS row = 128B: chunks 0..3 = {re|cos}, 4..7 = {im|sin}; slot = chunk^(row&7)
// (swizzle applied on the per-lane GLOBAL source; LDS dest lane-linear).
// Per K-step per wave: 16 ds_read_b128, 32 MFMA, 2 barriers — identical profile
// to the verified 73us kernel; 16 steps; 2000 blocks at HALF total FLOPs.
#define BM3 128
#define BN3 64
#define BK3 32

__global__ __launch_bounds__(256, 3) void gemm_dual(
    const _Float16* __restrict__ Ar, const _Float16* __restrict__ Ai,
    const _Float16* __restrict__ Bc, const _Float16* __restrict__ Bs,
    const float* __restrict__ re512f, const float* __restrict__ window,
    _Float16* __restrict__ frames)
{
    __shared__ _Float16 LA[BM3 * 64];   // 16 KB, rows [re(32)|im(32)] swizzled
    __shared__ _Float16 LB[BN3 * 64];   //  8 KB, rows [cos(32)|sin(32)] swizzled

    const int raw = blockIdx.x;                    // 0..1999
    const int idx = (raw & 7) * 250 + (raw >> 3);  // XCD-grouping bijection
    const int mt = idx >> 3;                       // 0..249
    const int nt = idx & 7;                        // 0..7
    const int m0 = mt * BM3;
    const int n0 = nt * BN3;

    const int tid  = threadIdx.x;
    const int w    = tid >> 6;         // wave 0..3
    const int lane = tid & 63;
    const int wm   = w & 1;            // M-half (64 rows)
    const int wn   = w >> 1;           // N-half (32 cols)
    const int row16 = lane & 15;
    const int quad  = lane >> 4;

    // staging: srow 0..7, swizzled chunk; chunks 0-3 read matrix0, 4-7 matrix1
    const int srow   = lane >> 3;
    const int schunk = (lane & 7) ^ srow;
    const _Float16* gA = ((schunk < 4) ? Ar : Ai)
                         + (size_t)(m0 + w*32 + srow) * KP2 + (schunk & 3) * 8;
    const _Float16* gB = ((schunk < 4) ? Bc : Bs)
                         + (size_t)(n0 + w*16 + srow) * KP2 + (schunk & 3) * 8;

    f32x4 aC[4][2] = {};
    f32x4 aS[4][2] = {};

    for (int k0 = 0; k0 < KP2; k0 += BK3) {
        #pragma unroll
        for (int t = 0; t < 4; t++)
            async_copy16(gA + (size_t)t*8*KP2 + k0, LA + (w*4 + t) * 512);
        #pragma unroll
        for (int t = 0; t < 2; t++)
            async_copy16(gB + (size_t)t*8*KP2 + k0, LB + (w*2 + t) * 512);
        __syncthreads();               // drain staging

        f16x8 ar[4], ai_[4], bc[2], bs_[2];
        #pragma unroll
        for (int i = 0; i < 4; i++) {
            const int rA = wm*64 + i*16 + row16;
            ar[i]  = *(const f16x8*)&LA[rA * 64 + ((quad)     ^ (rA & 7)) * 8];
            ai_[i] = *(const f16x8*)&LA[rA * 64 + ((4 + quad) ^ (rA & 7)) * 8];
        }
        #pragma unroll
        for (int j = 0; j < 2; j++) {
            const int rB = wn*32 + j*16 + row16;
            bc[j]  = *(const f16x8*)&LB[rB * 64 + ((quad)     ^ (rB & 7)) * 8];
            bs_[j] = *(const f16x8*)&LB[rB * 64 + ((4 + quad) ^ (rB & 7)) * 8];
        }
        #pragma unroll
        for (int i = 0; i < 4; i++)
            #pragma unroll
            for (int j = 0; j < 2; j++) {
                aC[i][j] = __builtin_amdgcn_mfma_f32_16x16x32_f16(ar[i],  bc[j],  aC[i][j], 0, 0, 0);
                aS[i][j] = __builtin_amdgcn_mfma_f32_16x16x32_f16(ai_[i], bs_[j], aS[i][j], 0, 0, 0);
            }
        __syncthreads();               // all reads retired before overwrite
    }

    // Epilogue. C/D layout: col = lane&15 (-> n), row = quad*4 + reg (-> m).
    // x[n] = C+S+t (win[n]);  x[1024-n] = C-S+t (win[1024-n]), t = (-1)^n re512/1024.
    #pragma unroll
    for (int j = 0; j < 2; j++) {
        const int n = n0 + wn*32 + j*16 + row16;           // 0..511
        const float wpos = window[n];
        const float wneg = window[(NFFT - n) & (NFFT - 1)]; // n=0 unused
        #pragma unroll
        for (int i = 0; i < 4; i++) {
            const int mrow = m0 + wm*64 + i*16 + quad*4;
            const float4 r5v = *(const float4*)&re512f[mrow];
            const float r5a[4] = {r5v.x, r5v.y, r5v.z, r5v.w};
            const f32x4 c = aC[i][j];
            const f32x4 s = aS[i][j];
            #pragma unroll
            for (int r = 0; r < 4; r++) {
                const float t = (n & 1) ? -r5a[r] : r5a[r];
                const size_t mbase = (size_t)(mrow + r) * NFFT;
                frames[mbase + n] = (_Float16)((c[r] + s[r] + t) * wpos);
                if (n) frames[mbase + NFFT - n] = (_Float16)((c[r] - s[r] + t) * wneg);
            }
        }
    }
}

// ---------------- deterministic overlap-add gather (verified) ----------------
#define OLA_G 64096   // OUT_LEN/8
__global__ __launch_bounds__(256) void ola_gather(const _Float16* __restrict__ frames,
                                                  float* __restrict__ out)
{
    const int idx = blockIdx.x * 256 + threadIdx.x;   // b*OLA_G + r, exact grid
    const int b = idx / OLA_G;
    const int r = idx - b * OLA_G;
    const int s0 = r << 3;
    int tlo = (s0 - 768) >> 8;  if (tlo < 0) tlo = 0;
    int thi = s0 >> 8;          if (thi > TFRAMES-1) thi = TFRAMES-1;
    float sum[8] = {};
    for (int t = tlo; t <= thi; ++t) {
        const f16x8 f = *(const f16x8*)&frames[((size_t)b * TFRAMES + t) * NFFT + (s0 - (t << 8))];
        #pragma unroll
        for (int i = 0; i < 8; i++) sum[i] += (float)f[i];
    }
    f32x4* o = (f32x4*)(out + (size_t)b * OUT_LEN + s0);
    o[0] = (f32x4){sum[0], sum[1], sum[2], sum[3]};
    o[1] = (f32x4){sum[4], sum[5], sum[6], sum[7]};
}

// ---------------- legacy pack kernels (fallback atomic path) ----------------
__global__ __launch_bounds__(256) void pack_A(const float* __restrict__ sre,
                                              const float* __restrict__ sim,
                                              uint4* __restrict__ Au)
{
    const int idx = blockIdx.x * 256 + threadIdx.x;
    const int m = idx >> 7;
    const int j = idx & 127;
    const int k0 = j * 4;
    const size_t base = (size_t)m * BINS + k0;
    union { _Float16 h[8]; uint4 u; } pk;
    if (j == 0) {
        const float re0   = sre[(size_t)m * BINS];
        const float re512 = sre[(size_t)m * BINS + 512];
        pk.h[0] = (_Float16)(re0   * (1.0f/1024.0f));
        pk.h[1] = (_Float16)(re512 * (1.0f/1024.0f));
        #pragma unroll
        for (int i = 1; i < 4; i++) {
            pk.h[2*i]   = (_Float16)( sre[base + i] * (1.0f/512.0f));
            pk.h[2*i+1] = (_Float16)(-sim[base + i] * (1.0f/512.0f));
        }
    } else {
        #pragma unroll
        for (int i = 0; i < 4; i++) {
            pk.h[2*i]   = (_Float16)( sre[base + i] * (1.0f/512.0f));
            pk.h[2*i+1] = (_Float16)(-sim[base + i] * (1.0f/512.0f));
        }
    }
    Au[idx] = pk.u;
}

__global__ __launch_bounds__(256) void pack_B(const float* __restrict__ dcos,
                                              const float* __restrict__ dsin,
                                              unsigned* __restrict__ Bu)
{
    const int idx = blockIdx.x * 256 + threadIdx.x;
    const int n = idx >> 9;
    const int p = idx & 511;
    float b0, b1;
    if (p == 0) {
        b0 = 1.0f;
        b1 = (n & 1) ? -1.0f : 1.0f;
    } else {
        const size_t base = (size_t)n * NFFT + p;
        b0 = dcos[base];
        b1 = dsin[base];
    }
    union { _Float16 h[2]; unsigned u; } pk;
    pk.h[0] = (_Float16)b0;
    pk.h[1] = (_Float16)b1;
    Bu[idx] = pk.u;
}

// ---------------- legacy 128x128 MFMA GEMM (atomic fallback) ----------------
#define BM 128
#define BN 128
#define BK 64

__global__ __launch_bounds__(256, 3) void gemm_f16_atomic(const _Float16* __restrict__ A,
                                                          const _Float16* __restrict__ B,
                                                          const float* __restrict__ window,
                                                          float* __restrict__ out)
{
    __shared__ _Float16 As[BM * BK];
    __shared__ _Float16 Bs[BN * BK];

    const int raw = blockIdx.x;
    const int idx = (raw & 7) * 250 + (raw >> 3);
    const int mt = idx >> 3;
    const int nt = idx & 7;
    const int m0 = mt * BM;
    const int n0 = nt * BN;

    const int tid  = threadIdx.x;
    const int w    = tid >> 6;
    const int lane = tid & 63;
    const int wm   = w & 1;
    const int wn   = w >> 1;
    const int row16 = lane & 15;
    const int quad  = lane >> 4;

    const int srow   = lane >> 3;
    const int schunk = (lane & 7) ^ srow;
    const _Float16* gA = A + (size_t)(m0 + w*32 + srow) * KP + schunk * 8;
    const _Float16* gB = B + (size_t)(n0 + w*32 + srow) * KP + schunk * 8;

    f32x4 acc[4][4] = {};

    for (int k0 = 0; k0 < KP; k0 += BK) {
        #pragma unroll
        for (int t = 0; t < 4; t++) {
            async_copy16(gA + (size_t)t*8*KP + k0, As + (w*4 + t) * 512);
            async_copy16(gB + (size_t)t*8*KP + k0, Bs + (w*4 + t) * 512);
        }
        __syncthreads();
        #pragma unroll
        for (int c = 0; c < 2; c++) {
            f16x8 af[4], bf[4];
            #pragma unroll
            for (int i = 0; i < 4; i++) {
                const int rowA = wm*64 + i*16 + row16;
                const int chA  = (c*4 + quad) ^ (row16 & 7);
                af[i] = *(const f16x8*)&As[rowA * BK + chA * 8];
            }
            #pragma unroll
            for (int j = 0; j < 4; j++) {
                const int rowB = wn*64 + j*16 + row16;
                const int chB  = (c*4 + quad) ^ (row16 & 7);
                bf[j] = *(const f16x8*)&Bs[rowB * BK + chB * 8];
            }
            #pragma unroll
            for (int i = 0; i < 4; i++)
                #pragma unroll
                for (int j = 0; j < 4; j++)
                    acc[i][j] = __builtin_amdgcn_mfma_f32_16x16x32_f16(af[i], bf[j], acc[i][j], 0, 0, 0);
        }
        __syncthreads();
    }

    #pragma unroll
    for (int j = 0; j < 4; j++) {
        const int n = n0 + wn*64 + j*16 + row16;
        const float win = window[n];
        #pragma unroll
        for (int i = 0; i < 4; i++) {
            const int mrow = m0 + wm*64 + i*16 + quad*4;
            const f32x4 c = acc[i][j];
            #pragma unroll
            for (int r = 0; r < 4; r++) {
                const int m = mrow + r;
                const int b = m / TFRAMES;
                const int t = m - b * TFRAMES;
                atomicAdd(&out[(size_t)b * OUT_LEN + (size_t)t * STEP + n], c[r] * win);
            }
        }
    }
}

// ---------------- round-1 fp32 fallback (known-correct) ----------------
#define MT 64
#define NT 64
#define KT 16
#define PAD 4
__global__ __launch_bounds__(256) void istft_gemm_ola_f32(
    const float* __restrict__ sre, const float* __restrict__ sim,
    const float* __restrict__ dcos, const float* __restrict__ dsin,
    const float* __restrict__ window, float* __restrict__ out)
{
    __shared__ float As_re[KT][MT + PAD];
    __shared__ float As_im[KT][MT + PAD];
    __shared__ float Bs_c[KT][NT + PAD];
    __shared__ float Bs_s[KT][NT + PAD];
    const int ntile = blockIdx.x & 15;
    const int mtile = blockIdx.x >> 4;
    const int m0 = mtile * MT, n0 = ntile * NT;
    const int tid = threadIdx.x;
    const int tx = tid & 15, ty = tid >> 4;
    const int lcol = tid & 15, lrow = tid >> 4;
    float acc[4][4] = {};
    for (int k0 = 0; k0 < BINS; k0 += KT) {
        const int k = k0 + lcol;
        const bool kvalid = (k < BINS);
        const float w = kvalid ? ((k == 0 || k == 512) ? (1.0f/1024.0f) : (2.0f/1024.0f)) : 0.0f;
        #pragma unroll
        for (int i = 0; i < 4; i++) {
            const int m = m0 + lrow + i*16;
            const size_t base = (size_t)m * BINS + k;
            As_re[lcol][lrow + i*16] = kvalid ?  w * sre[base] : 0.0f;
            As_im[lcol][lrow + i*16] = kvalid ? -w * sim[base] : 0.0f;
        }
        #pragma unroll
        for (int i = 0; i < 4; i++) {
            const int n = n0 + lrow + i*16;
            const size_t base = (size_t)n * NFFT + k;
            Bs_c[lcol][lrow + i*16] = kvalid ? dcos[base] : 0.0f;
            Bs_s[lcol][lrow + i*16] = kvalid ? dsin[base] : 0.0f;
        }
        __syncthreads();
        #pragma unroll
        for (int kk = 0; kk < KT; kk++) {
            const float4 ar = *(const float4*)&As_re[kk][ty*4];
            const float4 ai = *(const float4*)&As_im[kk][ty*4];
            const float4 bc = *(const float4*)&Bs_c[kk][tx*4];
            const float4 bs = *(const float4*)&Bs_s[kk][tx*4];
            const float a_r[4] = {ar.x, ar.y, ar.z, ar.w};
            const float a_i[4] = {ai.x, ai.y, ai.z, ai.w};
            const float b_c[4] = {bc.x, bc.y, bc.z, bc.w};
            const float b_s[4] = {bs.x, bs.y, bs.z, bs.w};
            #pragma unroll
            for (int i = 0; i < 4; i++)
                #pragma unroll
                for (int j = 0; j < 4; j++)
                    acc[i][j] += a_r[i]*b_c[j] + a_i[i]*b_s[j];
        }
        __syncthreads();
    }
    #pragma unroll
    for (int i = 0; i < 4; i++) {
        const int m = m0 + ty*4 + i;
        const int b = m / TFRAMES;
        const int t = m - b * TFRAMES;
        const size_t obase = (size_t)b * OUT_LEN + (size_t)t * STEP;
        #pragma unroll
        for (int j = 0; j < 4; j++) {
            const int n = n0 + tx*4 + j;
            atomicAdd(&out[obase + n], acc[i][j] * window[n]);
        }
    }
}

// ---------------- launch ----------------
extern "C" void kernel_launch(void* const* d_in, const int* in_sizes, int n_in,
                              void* d_out, int out_size, void* d_ws, size_t ws_size,
                              hipStream_t stream) {
    const float* sre    = (const float*)d_in[0];
    const float* sim    = (const float*)d_in[1];
    const float* dcos   = (const float*)d_in[2];
    const float* dsin   = (const float*)d_in[3];
    const float* window = (const float*)d_in[4];
    float* out = (float*)d_out;

    // fast-path workspace layout
    const size_t WS_AR = (size_t)M_TOTAL * KP2 * sizeof(_Float16);    // 32,768,000
    const size_t WS_AI = WS_AR;
    const size_t WS_R5 = (size_t)M_TOTAL * sizeof(float);             //    128,000
    const size_t WS_BC = (size_t)512 * KP2 * sizeof(_Float16);        //    524,288
    const size_t WS_BS = WS_BC;
    const size_t WS_FR = (size_t)M_TOTAL * NFFT * sizeof(_Float16);   // 65,536,000
    const size_t NEED  = WS_AR + WS_AI + WS_R5 + WS_BC + WS_BS + WS_FR;

    // legacy atomic-path workspace
    const size_t WS_A = (size_t)M_TOTAL * KP * sizeof(_Float16);
    const size_t WS_B = (size_t)NFFT    * KP * sizeof(_Float16);

    if (ws_size >= NEED) {
        char* p = (char*)d_ws;
        _Float16* Ar = (_Float16*)p;  p += WS_AR;
        _Float16* Ai = (_Float16*)p;  p += WS_AI;
        float*    r5 = (float*)p;     p += WS_R5;
        _Float16* Bc = (_Float16*)p;  p += WS_BC;
        _Float16* Bs = (_Float16*)p;  p += WS_BS;
        _Float16* fr = (_Float16*)p;

        pack_A2<<<(M_TOTAL * 64) / 256, 256, 0, stream>>>(sre, sim, window,
                                                          (uint4*)Ar, (uint4*)Ai, r5, fr);
        pack_B2<<<(512 * 64) / 256, 256, 0, stream>>>(dcos, dsin, (uint4*)Bc, (uint4*)Bs);

        const int grid = (M_TOTAL / BM3) * (KP2 / BN3);   // 250 * 8 = 2000
        gemm_dual<<<grid, 256, 0, stream>>>(Ar, Ai, Bc, Bs, r5, window, fr);
        ola_gather<<<(BATCH * OUT_LEN) / 2048, 256, 0, stream>>>(fr, out);
    } else if (ws_size >= WS_A + WS_B) {
        hipMemsetAsync(out, 0, (size_t)out_size * sizeof(float), stream);
        _Float16* Apk = (_Float16*)d_ws;
        _Float16* Bpk = (_Float16*)((char*)d_ws + WS_A);
        pack_A<<<(M_TOTAL * JPACK) / 256, 256, 0, stream>>>(sre, sim, (uint4*)Apk);
        pack_B<<<(NFFT * PAIRS) / 256, 256, 0, stream>>>(dcos, dsin, (unsigned*)Bpk);
        const int grid = (M_TOTAL / BM) * (NFFT / BN);
        gemm_f16_atomic<<<grid, 256, 0, stream>>>(Apk, Bpk, window, out);
    } else {
        hipMemsetAsync(out, 0, (size_t)out_size * sizeof(float), stream);
        const int grid = (M_TOTAL / MT) * (NFFT / NT);
        istft_gemm_ola_f32<<<grid, 256, 0, stream>>>(sre, sim, dcos, dsin, window, out);
    }
}

// Round 3
// 249.486 us; speedup vs baseline: 1.0426x; 1.0322x over previous
//
#include <hip/hip_runtime.h>

#define BATCH 16
#define TFRAMES 2000
#define BINS 513
#define NFFT 1024
#define STEP 256
#define OUT_LEN 512768            // (TFRAMES-1)*STEP + NFFT
#define M_TOTAL (BATCH*TFRAMES)   // 32000

// ---- legacy packed layout (fallback atomic path) ----
#define KP 1024
#define PAIRS 512
#define JPACK 128

// ---- symmetry-split layout (fast path) ----
// C[n] = sum_p Ar[p]*cos(2pi p n/1024), Ar[0]=re0/1024 (B_cos[n][0]=1), Ar[p]=re[p]/512
// S[n] = sum_p Ai[p]*sin(2pi p n/1024), Ai[p]=-im[p]/512, slot 0 dead (B_sin[n][0]=0)
// x[n]      = C[n]+S[n]+t,  x[1024-n] = C[n]-S[n]+t,  t=(-1)^n*re512/1024, n=0..511
// x[512]    = sum_k (-1)^k Ar[k] + re512/1024   (fused into pack_A2 wave-reduce)
#define KP2 512

typedef _Float16 f16x8 __attribute__((ext_vector_type(8)));
typedef float    f32x4 __attribute__((ext_vector_type(4)));

__device__ __forceinline__ void async_copy16(const void* g, void* l) {
    __builtin_amdgcn_global_load_lds(
        (const __attribute__((address_space(1))) unsigned*)g,
        (__attribute__((address_space(3))) unsigned*)l, 16, 0, 0);
}

// ---------------- fast-path pack kernels ----------------
// one wave (64 threads) per row m; thread j handles k = 8j..8j+7
__global__ __launch_bounds__(256) void pack_A2(const float* __restrict__ sre,
                                               const float* __restrict__ sim,
                                               const float* __restrict__ window,
                                               uint4* __restrict__ Ar,
                                               uint4* __restrict__ Ai,
                                               float* __restrict__ re512f,
                                               _Float16* __restrict__ frames)
{
    const int idx = blockIdx.x * 256 + threadIdx.x;   // m*64 + j, exact grid
    const int m = idx >> 6;
    const int j = idx & 63;
    const int k0 = j * 8;
    const size_t base = (size_t)m * BINS + k0;
    float ar[8], ai[8];
    #pragma unroll
    for (int i = 0; i < 8; i++) {
        ar[i] =  sre[base + i] * (1.0f/512.0f);
        ai[i] = -sim[base + i] * (1.0f/512.0f);
    }
    float r5 = 0.0f;
    if (j == 0) {
        ar[0] = sre[(size_t)m * BINS] * (1.0f/1024.0f);   // DC slot, B_cos[n][0]=1
        ai[0] = 0.0f;                                      // dead slot, B_sin[n][0]=0
        r5 = sre[(size_t)m * BINS + 512] * (1.0f/1024.0f);
        re512f[m] = r5;
    }
    union { _Float16 h[8]; uint4 u; } pr, pi;
    #pragma unroll
    for (int i = 0; i < 8; i++) { pr.h[i] = (_Float16)ar[i]; pi.h[i] = (_Float16)ai[i]; }
    Ar[idx] = pr.u;
    Ai[idx] = pi.u;

    // fused n=512 column: x[512] = sum_k (-1)^k Ar[k] + re512/1024 (f32 accumulate)
    float s = ar[0]-ar[1]+ar[2]-ar[3]+ar[4]-ar[5]+ar[6]-ar[7];
    #pragma unroll
    for (int off = 32; off > 0; off >>= 1) s += __shfl_xor(s, off);
    if (j == 0)
        frames[(size_t)m * NFFT + 512] = (_Float16)((s + r5) * window[512]);
}

__global__ __launch_bounds__(256) void pack_B2(const float* __restrict__ dcos,
                                               const float* __restrict__ dsin,
                                               uint4* __restrict__ Bc,
                                               uint4* __restrict__ Bs)
{
    const int idx = blockIdx.x * 256 + threadIdx.x;   // n*64 + j, exact grid (128 blocks)
    const int n = idx >> 6;
    const int j = idx & 63;
    const int k0 = j * 8;
    const size_t base = (size_t)n * NFFT + k0;
    union { _Float16 h[8]; uint4 u; } pc, ps;
    #pragma unroll
    for (int i = 0; i < 8; i++) {
        pc.h[i] = (_Float16)dcos[base + i];
        ps.h[i] = (_Float16)dsin[base + i];
    }
    if (j == 0) { pc.h[0] = (_Float16)1.0f; ps.h[0] = (_Float16)0.0f; }
    Bc[idx] = pc.u;
    Bs[idx] = ps.u;
}

// ---------------- dual-accumulator symmetry GEMM, BK=64, 8 K-steps ----------
// Block: 128(M) x 64(N of half-domain), 2x2 waves, dual 64x32 per wave.
// LDS: four PLANAR tiles with 128B rows (8 x 16B chunks), proven 8-slot
// swizzle slot = chunk^(row&7) per plane, applied on the per-lane GLOBAL
// source; LDS dest lane-linear (global_load_lds rule).
// Per K-step per wave: 12 async copies (block), 24 ds_read_b128, 32 MFMA,
// 2 barriers — proven per-step MFMA density at HALF the step count (8 vs 16).
#define BM3 128
#define BN3 64
#define BK3 64    // halves per matrix per step -> 8 steps over KP2=512

__global__ __launch_bounds__(256, 3) void gemm_dual(
    const _Float16* __restrict__ Ar, const _Float16* __restrict__ Ai,
    const _Float16* __restrict__ Bc, const _Float16* __restrict__ Bs,
    const float* __restrict__ re512f, const float* __restrict__ window,
    _Float16* __restrict__ frames)
{
    __shared__ _Float16 LAr[BM3 * BK3];   // 16 KB
    __shared__ _Float16 LAi[BM3 * BK3];   // 16 KB
    __shared__ _Float16 LBc[BN3 * BK3];   //  8 KB
    __shared__ _Float16 LBs[BN3 * BK3];   //  8 KB

    const int raw = blockIdx.x;                    // 0..1999
    const int idx = (raw & 7) * 250 + (raw >> 3);  // XCD-grouping bijection
    const int mt = idx >> 3;                       // 0..249
    const int nt = idx & 7;                        // 0..7
    const int m0 = mt * BM3;
    const int n0 = nt * BN3;

    const int tid  = threadIdx.x;
    const int w    = tid >> 6;         // wave 0..3
    const int lane = tid & 63;
    const int wm   = w & 1;            // M-half (64 rows)
    const int wn   = w >> 1;           // N-half (32 cols)
    const int row16 = lane & 15;
    const int quad  = lane >> 4;

    // staging: srow 0..7, swizzled chunk slot (applied to global source)
    const int srow  = lane >> 3;
    const int sslot = (lane & 7) ^ srow;
    const _Float16* gAr = Ar + (size_t)(m0 + w*32 + srow) * KP2 + sslot * 8;
    const _Float16* gAi = Ai + (size_t)(m0 + w*32 + srow) * KP2 + sslot * 8;
    const _Float16* gBc = Bc + (size_t)(n0 + w*16 + srow) * KP2 + sslot * 8;
    const _Float16* gBs = Bs + (size_t)(n0 + w*16 + srow) * KP2 + sslot * 8;

    f32x4 aC[4][2] = {};
    f32x4 aS[4][2] = {};

    for (int k0 = 0; k0 < KP2; k0 += BK3) {        // 8 steps
        #pragma unroll
        for (int t = 0; t < 4; t++) {
            async_copy16(gAr + (size_t)t*8*KP2 + k0, LAr + (w*32 + t*8) * BK3);
            async_copy16(gAi + (size_t)t*8*KP2 + k0, LAi + (w*32 + t*8) * BK3);
        }
        #pragma unroll
        for (int t = 0; t < 2; t++) {
            async_copy16(gBc + (size_t)t*8*KP2 + k0, LBc + (w*16 + t*8) * BK3);
            async_copy16(gBs + (size_t)t*8*KP2 + k0, LBs + (w*16 + t*8) * BK3);
        }
        __syncthreads();               // drain staging

        #pragma unroll
        for (int ks = 0; ks < 2; ks++) {
            f16x8 ar[4], ai_[4], bc[2], bs_[2];
            #pragma unroll
            for (int i = 0; i < 4; i++) {
                const int rA = wm*64 + i*16 + row16;
                const int sl = ((ks*4 + quad) ^ (rA & 7)) * 8;
                ar[i]  = *(const f16x8*)&LAr[rA * BK3 + sl];
                ai_[i] = *(const f16x8*)&LAi[rA * BK3 + sl];
            }
            #pragma unroll
            for (int j = 0; j < 2; j++) {
                const int rB = wn*32 + j*16 + row16;
                const int sl = ((ks*4 + quad) ^ (rB & 7)) * 8;
                bc[j]  = *(const f16x8*)&LBc[rB * BK3 + sl];
                bs_[j] = *(const f16x8*)&LBs[rB * BK3 + sl];
            }
            #pragma unroll
            for (int i = 0; i < 4; i++)
                #pragma unroll
                for (int j = 0; j < 2; j++) {
                    aC[i][j] = __builtin_amdgcn_mfma_f32_16x16x32_f16(ar[i],  bc[j],  aC[i][j], 0, 0, 0);
                    aS[i][j] = __builtin_amdgcn_mfma_f32_16x16x32_f16(ai_[i], bs_[j], aS[i][j], 0, 0, 0);
                }
        }
        __syncthreads();               // all reads retired before overwrite
    }

    // Epilogue (verified round 2). C/D layout: col = lane&15 (-> n), row = quad*4 + reg.
    // x[n] = C+S+t (win[n]);  x[1024-n] = C-S+t (win[1024-n]), t = (-1)^n re512/1024.
    #pragma unroll
    for (int j = 0; j < 2; j++) {
        const int n = n0 + wn*32 + j*16 + row16;           // 0..511
        const float wpos = window[n];
        const float wneg = window[(NFFT - n) & (NFFT - 1)]; // n=0 unused
        #pragma unroll
        for (int i = 0; i < 4; i++) {
            const int mrow = m0 + wm*64 + i*16 + quad*4;
            const float4 r5v = *(const float4*)&re512f[mrow];
            const float r5a[4] = {r5v.x, r5v.y, r5v.z, r5v.w};
            const f32x4 c = aC[i][j];
            const f32x4 s = aS[i][j];
            #pragma unroll
            for (int r = 0; r < 4; r++) {
                const float t = (n & 1) ? -r5a[r] : r5a[r];
                const size_t mbase = (size_t)(mrow + r) * NFFT;
                frames[mbase + n] = (_Float16)((c[r] + s[r] + t) * wpos);
                if (n) frames[mbase + NFFT - n] = (_Float16)((c[r] - s[r] + t) * wneg);
            }
        }
    }
}

// ---------------- deterministic overlap-add gather (verified) ----------------
#define OLA_G 64096   // OUT_LEN/8
__global__ __launch_bounds__(256) void ola_gather(const _Float16* __restrict__ frames,
                                                  float* __restrict__ out)
{
    const int idx = blockIdx.x * 256 + threadIdx.x;   // b*OLA_G + r, exact grid
    const int b = idx / OLA_G;
    const int r = idx - b * OLA_G;
    const int s0 = r << 3;
    int tlo = (s0 - 768) >> 8;  if (tlo < 0) tlo = 0;
    int thi = s0 >> 8;          if (thi > TFRAMES-1) thi = TFRAMES-1;
    float sum[8] = {};
    for (int t = tlo; t <= thi; ++t) {
        const f16x8 f = *(const f16x8*)&frames[((size_t)b * TFRAMES + t) * NFFT + (s0 - (t << 8))];
        #pragma unroll
        for (int i = 0; i < 8; i++) sum[i] += (float)f[i];
    }
    f32x4* o = (f32x4*)(out + (size_t)b * OUT_LEN + s0);
    o[0] = (f32x4){sum[0], sum[1], sum[2], sum[3]};
    o[1] = (f32x4){sum[4], sum[5], sum[6], sum[7]};
}

// ---------------- legacy pack kernels (fallback atomic path) ----------------
__global__ __launch_bounds__(256) void pack_A(const float* __restrict__ sre,
                                              const float* __restrict__ sim,
                                              uint4* __restrict__ Au)
{
    const int idx = blockIdx.x * 256 + threadIdx.x;
    const int m = idx >> 7;
    const int j = idx & 127;
    const int k0 = j * 4;
    const size_t base = (size_t)m * BINS + k0;
    union { _Float16 h[8]; uint4 u; } pk;
    if (j == 0) {
        const float re0   = sre[(size_t)m * BINS];
        const float re512 = sre[(size_t)m * BINS + 512];
        pk.h[0] = (_Float16)(re0   * (1.0f/1024.0f));
        pk.h[1] = (_Float16)(re512 * (1.0f/1024.0f));
        #pragma unroll
        for (int i = 1; i < 4; i++) {
            pk.h[2*i]   = (_Float16)( sre[base + i] * (1.0f/512.0f));
            pk.h[2*i+1] = (_Float16)(-sim[base + i] * (1.0f/512.0f));
        }
    } else {
        #pragma unroll
        for (int i = 0; i < 4; i++) {
            pk.h[2*i]   = (_Float16)( sre[base + i] * (1.0f/512.0f));
            pk.h[2*i+1] = (_Float16)(-sim[base + i] * (1.0f/512.0f));
        }
    }
    Au[idx] = pk.u;
}

__global__ __launch_bounds__(256) void pack_B(const float* __restrict__ dcos,
                                              const float* __restrict__ dsin,
                                              unsigned* __restrict__ Bu)
{
    const int idx = blockIdx.x * 256 + threadIdx.x;
    const int n = idx >> 9;
    const int p = idx & 511;
    float b0, b1;
    if (p == 0) {
        b0 = 1.0f;
        b1 = (n & 1) ? -1.0f : 1.0f;
    } else {
        const size_t base = (size_t)n * NFFT + p;
        b0 = dcos[base];
        b1 = dsin[base];
    }
    union { _Float16 h[2]; unsigned u; } pk;
    pk.h[0] = (_Float16)b0;
    pk.h[1] = (_Float16)b1;
    Bu[idx] = pk.u;
}

// ---------------- legacy 128x128 MFMA GEMM (atomic fallback) ----------------
#define BM 128
#define BN 128
#define BK 64

__global__ __launch_bounds__(256, 3) void gemm_f16_atomic(const _Float16* __restrict__ A,
                                                          const _Float16* __restrict__ B,
                                                          const float* __restrict__ window,
                                                          float* __restrict__ out)
{
    __shared__ _Float16 As[BM * BK];
    __shared__ _Float16 Bs[BN * BK];

    const int raw = blockIdx.x;
    const int idx = (raw & 7) * 250 + (raw >> 3);
    const int mt = idx >> 3;
    const int nt = idx & 7;
    const int m0 = mt * BM;
    const int n0 = nt * BN;

    const int tid  = threadIdx.x;
    const int w    = tid >> 6;
    const int lane = tid & 63;
    const int wm   = w & 1;
    const int wn   = w >> 1;
    const int row16 = lane & 15;
    const int quad  = lane >> 4;

    const int srow   = lane >> 3;
    const int schunk = (lane & 7) ^ srow;
    const _Float16* gA = A + (size_t)(m0 + w*32 + srow) * KP + schunk * 8;
    const _Float16* gB = B + (size_t)(n0 + w*32 + srow) * KP + schunk * 8;

    f32x4 acc[4][4] = {};

    for (int k0 = 0; k0 < KP; k0 += BK) {
        #pragma unroll
        for (int t = 0; t < 4; t++) {
            async_copy16(gA + (size_t)t*8*KP + k0, As + (w*4 + t) * 512);
            async_copy16(gB + (size_t)t*8*KP + k0, Bs + (w*4 + t) * 512);
        }
        __syncthreads();
        #pragma unroll
        for (int c = 0; c < 2; c++) {
            f16x8 af[4], bf[4];
            #pragma unroll
            for (int i = 0; i < 4; i++) {
                const int rowA = wm*64 + i*16 + row16;
                const int chA  = (c*4 + quad) ^ (row16 & 7);
                af[i] = *(const f16x8*)&As[rowA * BK + chA * 8];
            }
            #pragma unroll
            for (int j = 0; j < 4; j++) {
                const int rowB = wn*64 + j*16 + row16;
                const int chB  = (c*4 + quad) ^ (row16 & 7);
                bf[j] = *(const f16x8*)&Bs[rowB * BK + chB * 8];
            }
            #pragma unroll
            for (int i = 0; i < 4; i++)
                #pragma unroll
                for (int j = 0; j < 4; j++)
                    acc[i][j] = __builtin_amdgcn_mfma_f32_16x16x32_f16(af[i], bf[j], acc[i][j], 0, 0, 0);
        }
        __syncthreads();
    }

    #pragma unroll
    for (int j = 0; j < 4; j++) {
        const int n = n0 + wn*64 + j*16 + row16;
        const float win = window[n];
        #pragma unroll
        for (int i = 0; i < 4; i++) {
            const int mrow = m0 + wm*64 + i*16 + quad*4;
            const f32x4 c = acc[i][j];
            #pragma unroll
            for (int r = 0; r < 4; r++) {
                const int m = mrow + r;
                const int b = m / TFRAMES;
                const int t = m - b * TFRAMES;
                atomicAdd(&out[(size_t)b * OUT_LEN + (size_t)t * STEP + n], c[r] * win);
            }
        }
    }
}

// ---------------- round-1 fp32 fallback (known-correct) ----------------
#define MT 64
#define NT 64
#define KT 16
#define PAD 4
__global__ __launch_bounds__(256) void istft_gemm_ola_f32(
    const float* __restrict__ sre, const float* __restrict__ sim,
    const float* __restrict__ dcos, const float* __restrict__ dsin,
    const float* __restrict__ window, float* __restrict__ out)
{
    __shared__ float As_re[KT][MT + PAD];
    __shared__ float As_im[KT][MT + PAD];
    __shared__ float Bs_c[KT][NT + PAD];
    __shared__ float Bs_s[KT][NT + PAD];
    const int ntile = blockIdx.x & 15;
    const int mtile = blockIdx.x >> 4;
    const int m0 = mtile * MT, n0 = ntile * NT;
    const int tid = threadIdx.x;
    const int tx = tid & 15, ty = tid >> 4;
    const int lcol = tid & 15, lrow = tid >> 4;
    float acc[4][4] = {};
    for (int k0 = 0; k0 < BINS; k0 += KT) {
        const int k = k0 + lcol;
        const bool kvalid = (k < BINS);
        const float w = kvalid ? ((k == 0 || k == 512) ? (1.0f/1024.0f) : (2.0f/1024.0f)) : 0.0f;
        #pragma unroll
        for (int i = 0; i < 4; i++) {
            const int m = m0 + lrow + i*16;
            const size_t base = (size_t)m * BINS + k;
            As_re[lcol][lrow + i*16] = kvalid ?  w * sre[base] : 0.0f;
            As_im[lcol][lrow + i*16] = kvalid ? -w * sim[base] : 0.0f;
        }
        #pragma unroll
        for (int i = 0; i < 4; i++) {
            const int n = n0 + lrow + i*16;
            const size_t base = (size_t)n * NFFT + k;
            Bs_c[lcol][lrow + i*16] = kvalid ? dcos[base] : 0.0f;
            Bs_s[lcol][lrow + i*16] = kvalid ? dsin[base] : 0.0f;
        }
        __syncthreads();
        #pragma unroll
        for (int kk = 0; kk < KT; kk++) {
            const float4 ar = *(const float4*)&As_re[kk][ty*4];
            const float4 ai = *(const float4*)&As_im[kk][ty*4];
            const float4 bc = *(const float4*)&Bs_c[kk][tx*4];
            const float4 bs = *(const float4*)&Bs_s[kk][tx*4];
            const float a_r[4] = {ar.x, ar.y, ar.z, ar.w};
            const float a_i[4] = {ai.x, ai.y, ai.z, ai.w};
            const float b_c[4] = {bc.x, bc.y, bc.z, bc.w};
            const float b_s[4] = {bs.x, bs.y, bs.z, bs.w};
            #pragma unroll
            for (int i = 0; i < 4; i++)
                #pragma unroll
                for (int j = 0; j < 4; j++)
                    acc[i][j] += a_r[i]*b_c[j] + a_i[i]*b_s[j];
        }
        __syncthreads();
    }
    #pragma unroll
    for (int i = 0; i < 4; i++) {
        const int m = m0 + ty*4 + i;
        const int b = m / TFRAMES;
        const int t = m - b * TFRAMES;
        const size_t obase = (size_t)b * OUT_LEN + (size_t)t * STEP;
        #pragma unroll
        for (int j = 0; j < 4; j++) {
            const int n = n0 + tx*4 + j;
            atomicAdd(&out[obase + n], acc[i][j] * window[n]);
        }
    }
}

// ---------------- launch ----------------
extern "C" void kernel_launch(void* const* d_in, const int* in_sizes, int n_in,
                              void* d_out, int out_size, void* d_ws, size_t ws_size,
                              hipStream_t stream) {
    const float* sre    = (const float*)d_in[0];
    const float* sim    = (const float*)d_in[1];
    const float* dcos   = (const float*)d_in[2];
    const float* dsin   = (const float*)d_in[3];
    const float* window = (const float*)d_in[4];
    float* out = (float*)d_out;

    // fast-path workspace layout
    const size_t WS_AR = (size_t)M_TOTAL * KP2 * sizeof(_Float16);    // 32,768,000
    const size_t WS_AI = WS_AR;
    const size_t WS_R5 = (size_t)M_TOTAL * sizeof(float);             //    128,000
    const size_t WS_BC = (size_t)512 * KP2 * sizeof(_Float16);        //    524,288
    const size_t WS_BS = WS_BC;
    const size_t WS_FR = (size_t)M_TOTAL * NFFT * sizeof(_Float16);   // 65,536,000
    const size_t NEED  = WS_AR + WS_AI + WS_R5 + WS_BC + WS_BS + WS_FR;

    // legacy atomic-path workspace
    const size_t WS_A = (size_t)M_TOTAL * KP * sizeof(_Float16);
    const size_t WS_B = (size_t)NFFT    * KP * sizeof(_Float16);

    if (ws_size >= NEED) {
        char* p = (char*)d_ws;
        _Float16* Ar = (_Float16*)p;  p += WS_AR;
        _Float16* Ai = (_Float16*)p;  p += WS_AI;
        float*    r5 = (float*)p;     p += WS_R5;
        _Float16* Bc = (_Float16*)p;  p += WS_BC;
        _Float16* Bs = (_Float16*)p;  p += WS_BS;
        _Float16* fr = (_Float16*)p;

        pack_A2<<<(M_TOTAL * 64) / 256, 256, 0, stream>>>(sre, sim, window,
                                                          (uint4*)Ar, (uint4*)Ai, r5, fr);
        pack_B2<<<(512 * 64) / 256, 256, 0, stream>>>(dcos, dsin, (uint4*)Bc, (uint4*)Bs);

        const int grid = (M_TOTAL / BM3) * (KP2 / BN3);   // 250 * 8 = 2000
        gemm_dual<<<grid, 256, 0, stream>>>(Ar, Ai, Bc, Bs, r5, window, fr);
        ola_gather<<<(BATCH * OUT_LEN) / 2048, 256, 0, stream>>>(fr, out);
    } else if (ws_size >= WS_A + WS_B) {
        hipMemsetAsync(out, 0, (size_t)out_size * sizeof(float), stream);
        _Float16* Apk = (_Float16*)d_ws;
        _Float16* Bpk = (_Float16*)((char*)d_ws + WS_A);
        pack_A<<<(M_TOTAL * JPACK) / 256, 256, 0, stream>>>(sre, sim, (uint4*)Apk);
        pack_B<<<(NFFT * PAIRS) / 256, 256, 0, stream>>>(dcos, dsin, (unsigned*)Bpk);
        const int grid = (M_TOTAL / BM) * (NFFT / BN);
        gemm_f16_atomic<<<grid, 256, 0, stream>>>(Apk, Bpk, window, out);
    } else {
        hipMemsetAsync(out, 0, (size_t)out_size * sizeof(float), stream);
        const int grid = (M_TOTAL / MT) * (NFFT / NT);
        istft_gemm_ola_f32<<<grid, 256, 0, stream>>>(sre, sim, dcos, dsin, window, out);
    }
}